// Round 8
// baseline (589.937 us; speedup 1.0000x reference)
//
#include <hip/hip_runtime.h>

// LSTM RNN_20263655702953 — MI355X (gfx950), round 12.
//
// Reference quirk: hs[:, -1, :] selects BATCH index 511 => single sequential
// LSTM chain (1024 steps, H=64), then (1024,64)@(64,2) projection.
//
// R12 = R10's K-split structure with the waterfall bug fixed + R4's proven
// trims. Session evidence:
//  - R10 (K-split) lost to R4 ONLY because readlane(hb, 16*q+j) has a
//    runtime lane index -> compiler waterfall (~250 extra busy-cy/step).
//    Fix: branch on wave-uniform q; each arm uses COMPILE-TIME lane
//    constants (R4-proven zero-latency v_readlane).
//  - R11 showed direct per-step global hist stores regress vs hring
//    staging (+addr VALU on wave0, the barrier pacer). hring restored.
//  - lgkm-only barrier + hring: flush stores stay in flight across steps.
//  - exp2 premul (v_exp_f32 is 2^x) saves a mul per transcendental.
// Structure per step, all 4 waves symmetric:
//   wave q owns h[16q..16q+16): 16 const-RL + 64 FMA (4 rows x 16-slice,
//   w[4][16]=64 VGPR) -> 1 ds_write_b128 partial -> lgkm barrier ->
//   4 contiguous ds_read_b128 -> 12 adds -> 4 acts + c,h update (replicated
//   in every wave so next step's RL is in-wave).
// Model ~530cy/step @1.65GHz => ~330us. Falsifier: >=430us clean => exchange
// latency floor; revert to R4.

#define T_LEN 1024
#define BATCH 512
#define HID   64
#define LOG2E 1.4426950408889634f

__device__ __forceinline__ float fast_rcp(float x) {
    return __builtin_amdgcn_rcpf(x);  // v_rcp_f32, ~1e-7 rel err
}
__device__ __forceinline__ float fast_exp2(float x) {
    float r;
    asm("v_exp_f32 %0, %1" : "=v"(r) : "v"(x));   // 2^x, transcendental pipe
    return r;
}
__device__ __forceinline__ void fast_barrier() {
    // LDS-only drain + barrier; deliberately no vmcnt (hist stores in flight)
    asm volatile("s_waitcnt lgkmcnt(0)\n\ts_barrier" ::: "memory");
}

// sigmoid(x) = rcp(1 + 2^(-log2e*x))
__device__ __forceinline__ float fast_sigmoid(float x) {
    return fast_rcp(1.0f + fast_exp2(-LOG2E * x));
}
// tanh(x) = 2*rcp(1 + 2^(-2*log2e*x)) - 1
__device__ __forceinline__ float fast_tanh2(float x) {
    return fmaf(2.0f, fast_rcp(1.0f + fast_exp2(-2.0f * LOG2E * x)), -1.0f);
}

#define RL16C(DST, OFF)                                                     \
    _Pragma("unroll")                                                       \
    for (int k = 0; k < 16; ++k)                                            \
        DST[k] = __builtin_amdgcn_readlane(hb, (OFF) + k);

__global__ __launch_bounds__(256, 1)
void lstm_seq_kernel(const float* __restrict__ x,
                     const float* __restrict__ W_ih,
                     const float* __restrict__ W_hh,
                     const float* __restrict__ b_ih,
                     const float* __restrict__ b_hh,
                     const float* __restrict__ W_fc,
                     const float* __restrict__ b_fc,
                     float* __restrict__ out,
                     float* __restrict__ hist)   // d_ws: 1024*64 floats
{
    __shared__ float  xs[2 * T_LEN];        // 8 KB: x[:,511,:]
    __shared__ float4 part[2][4][HID];      // 8 KB: [buf][wave q][unit] = (i,f,g,o) partials
    __shared__ float  hring[64 * HID];      // 16 KB: ring of last 64 h (wave 0 only)

    const int tid  = threadIdx.x;
    const int lane = tid & 63;
    const int q    = tid >> 6;              // wave id = K-slice owner

    // ---- stage x[:,511,:] into LDS (one-time)
    for (int j = 0; j < 4; ++j) {
        int t = tid + j * 256;              // 0..1023
        const float2 v = *(const float2*)(x + (size_t)(t * BATCH + (BATCH - 1)) * 2);
        xs[2 * t]     = v.x;
        xs[2 * t + 1] = v.y;
    }

    // ---- weights: lane l, wave q holds W_hh[g*64+l][16q+j], g=0..3, j=0..15
    float w[4][16];
    #pragma unroll
    for (int g = 0; g < 4; ++g) {
        const float4* wr = (const float4*)(W_hh + (size_t)(g * HID + lane) * HID + 16 * q);
        #pragma unroll
        for (int k = 0; k < 4; ++k) {
            float4 v = wr[k];
            w[g][4*k+0] = v.x; w[g][4*k+1] = v.y;
            w[g][4*k+2] = v.z; w[g][4*k+3] = v.w;
        }
    }
    // x+bias contribution folded into wave 0's partial only (masked, branchless)
    float wi0s[4], wi1s[4], bss[4];
    {
        const float m = (q == 0) ? 1.0f : 0.0f;
        #pragma unroll
        for (int g = 0; g < 4; ++g) {
            const int row = g * HID + lane;
            wi0s[g] = m * W_ih[row * 2 + 0];
            wi1s[g] = m * W_ih[row * 2 + 1];
            bss[g]  = m * (b_ih[row] + b_hh[row]);
        }
    }
    __syncthreads();                        // xs visible everywhere

    float hval = 0.0f;   // lane l holds h[l]  (replicated in every wave)
    float cval = 0.0f;   // lane l holds c[l]

    for (int t = 0; t < T_LEN; ++t) {
        const float2 xv = *(const float2*)(xs + 2 * t);   // uniform bcast
        const int hb = __float_as_int(hval);

        // ---- h broadcast: this wave's 16-slice, COMPILE-TIME lane indices
        // (branch on wave-uniform q; each arm is 16 constant v_readlane —
        //  the zero-latency path R4 proved; no waterfall)
        int hs[16];
        if      (q == 0) { RL16C(hs, 0)  }
        else if (q == 1) { RL16C(hs, 16) }
        else if (q == 2) { RL16C(hs, 32) }
        else             { RL16C(hs, 48) }
        __builtin_amdgcn_sched_barrier(0);

        // seed (wave 0 carries x+bias; others start at 0) — branchless
        float a0 = fmaf(wi1s[0], xv.y, fmaf(wi0s[0], xv.x, bss[0]));
        float a1 = fmaf(wi1s[1], xv.y, fmaf(wi0s[1], xv.x, bss[1]));
        float a2 = fmaf(wi1s[2], xv.y, fmaf(wi0s[2], xv.x, bss[2]));
        float a3 = fmaf(wi1s[3], xv.y, fmaf(wi0s[3], xv.x, bss[3]));

        // ---- 64 FMAs: 4 gate rows x 16-wide K-slice (4 independent chains)
        #pragma unroll
        for (int j = 0; j < 16; ++j) {
            const float hj = __int_as_float(hs[j]);
            a0 = fmaf(w[0][j], hj, a0);
            a1 = fmaf(w[1][j], hj, a1);
            a2 = fmaf(w[2][j], hj, a2);
            a3 = fmaf(w[3][j], hj, a3);
        }

        // ---- publish partials: ONE contiguous b128 write (conflict-free)
        const int buf = t & 1;
        part[buf][q][lane] = make_float4(a0, a1, a2, a3);
        fast_barrier();                      // the only per-step barrier (lgkm-only)

        // ---- reduce: 4 contiguous conflict-free ds_read_b128
        const float4 p0 = part[buf][0][lane];
        const float4 p1 = part[buf][1][lane];
        const float4 p2 = part[buf][2][lane];
        const float4 p3 = part[buf][3][lane];
        const float s0 = (p0.x + p1.x) + (p2.x + p3.x);
        const float s1 = (p0.y + p1.y) + (p2.y + p3.y);
        const float s2 = (p0.z + p1.z) + (p2.z + p3.z);
        const float s3 = (p0.w + p1.w) + (p2.w + p3.w);

        // ---- activations (4 independent chains) + lane-local update
        const float gi = fast_sigmoid(s0);
        const float gf = fast_sigmoid(s1);
        const float gg = fast_tanh2(s2);
        const float go = fast_sigmoid(s3);
        cval = fmaf(gf, cval, gi * gg);
        hval = go * fast_tanh2(cval);

        // h history: wave 0 stages in hring (1 ds_write/step; flush every 64
        // steps; global stores fly across the lgkm-only barrier)
        if (q == 0) {
            hring[(t & 63) * HID + lane] = hval;
            if ((t & 63) == 63) {
                float4*       dst = (float4*)(hist + (t - 63) * HID);
                const float4* src = (const float4*)hring;
                #pragma unroll
                for (int j = 0; j < 16; ++j)     // 4096 floats, coalesced
                    dst[lane + 64 * j] = src[lane + 64 * j];
            }
        }
    }

    __syncthreads();  // full drain: wave0's hist stores retired & visible

    // ---- projection: out[t,o] = b_fc[o] + dot(W_fc[o,:], hist[t,:])
    #pragma unroll
    for (int j = 0; j < 8; ++j) {
        const int idx = tid + j * 256;      // 0..2047, coalesced stores
        const int t   = idx >> 1;
        const int o   = idx & 1;
        const float4* hv4 = (const float4*)(hist + t * HID);
        const float4* wv  = (const float4*)(W_fc + o * HID);
        float p0 = 0.f, p1 = 0.f, p2 = 0.f, p3 = 0.f;
        #pragma unroll
        for (int k = 0; k < HID / 4; ++k) {
            float4 h4 = hv4[k], w4 = wv[k];
            p0 = fmaf(h4.x, w4.x, p0);
            p1 = fmaf(h4.y, w4.y, p1);
            p2 = fmaf(h4.z, w4.z, p2);
            p3 = fmaf(h4.w, w4.w, p3);
        }
        out[idx] = b_fc[o] + ((p0 + p1) + (p2 + p3));
    }
}

extern "C" void kernel_launch(void* const* d_in, const int* in_sizes, int n_in,
                              void* d_out, int out_size, void* d_ws, size_t ws_size,
                              hipStream_t stream) {
    const float* x    = (const float*)d_in[0];
    const float* W_ih = (const float*)d_in[1];
    const float* W_hh = (const float*)d_in[2];
    const float* b_ih = (const float*)d_in[3];
    const float* b_hh = (const float*)d_in[4];
    const float* W_fc = (const float*)d_in[5];
    const float* b_fc = (const float*)d_in[6];
    float* out  = (float*)d_out;
    float* hist = (float*)d_ws;   // needs 1024*64*4 = 256 KB

    lstm_seq_kernel<<<dim3(1), dim3(256), 0, stream>>>(
        x, W_ih, W_hh, b_ih, b_hh, W_fc, b_fc, out, hist);
}